// Round 11
// baseline (5221.059 us; speedup 1.0000x reference)
//
#include <hip/hip_runtime.h>

#define FPS_N 32768
#define FPS_M 2048
#define FPS_B 16
#define BLK_PER_B 8
#define FPS_T 576                 // 9 waves: wave 0 = comm, waves 1-8 = scan
#define SCT 512                   // scan threads
#define PTS (FPS_N / BLK_PER_B)   // 4096 points per block
#define PPT (PTS / SCT)           // 8 points per scan thread

typedef unsigned long long ull;

// 64-bit max step via DPP (VALU pipe, ~5 cyc) instead of __shfl (ds_bpermute,
// ~40-80 cyc). old = self -> masked-off / invalid lanes return self, making
// the max a no-op there (identity-safe without bound_ctrl).
#define DPP_MAX_STEP(ctrl, rmask)                                              \
    {                                                                          \
        unsigned plo = (unsigned)__builtin_amdgcn_update_dpp(                  \
            (int)lo, (int)lo, (ctrl), (rmask), 0xf, false);                    \
        unsigned phi = (unsigned)__builtin_amdgcn_update_dpp(                  \
            (int)hi, (int)hi, (ctrl), (rmask), 0xf, false);                    \
        if (phi > hi || (phi == hi && plo > lo)) { hi = phi; lo = plo; }       \
    }

__device__ __forceinline__ ull wave_max_u64_dpp(ull v) {
    unsigned lo = (unsigned)v, hi = (unsigned)(v >> 32);
    DPP_MAX_STEP(0x111, 0xf);     // row_shr:1
    DPP_MAX_STEP(0x112, 0xf);     // row_shr:2
    DPP_MAX_STEP(0x114, 0xf);     // row_shr:4
    DPP_MAX_STEP(0x118, 0xf);     // row_shr:8   -> lane 15/31/47/63 = row max
    DPP_MAX_STEP(0x142, 0xa);     // row_bcast:15 -> lane 31/63 = half max
    DPP_MAX_STEP(0x143, 0xc);     // row_bcast:31 -> lane 63 = wave max
    return ((ull)hi << 32) | lo;  // valid in lane 63
}

__device__ __forceinline__ ull max8_u64_dpp(ull v) {
    unsigned lo = (unsigned)v, hi = (unsigned)(v >> 32);
    DPP_MAX_STEP(0x111, 0xf);     // lanes 0-7 carry the slots; lane 7 = max
    DPP_MAX_STEP(0x112, 0xf);
    DPP_MAX_STEP(0x114, 0xf);
    return ((ull)hi << 32) | lo;  // valid in lane 7
}

// FPS split 8 ways per batch, cooperative launch, wave-specialized.
// Round-11 vs round-10: (a) s_sleep stagger removed (+0.27 ms confirmed cost);
// (b) all shfl reduce chains -> DPP (two 6-deep ds_bpermute chains were
// ~600-900 cyc/step of serial DS latency); (c) winner coords posted to LDS by
// SELF-SELECTED lanes straight from their polled payload word (no 3-shfl
// gather); lane 0's workgroup-release of swtag drains the wave's DS queue,
// ordering the coord writes.
// Protocol (from rounds 8-10): each block publishes 4 self-validating relaxed
// agent words (line-major, 4 lines x 8 slots per parity):
//   wd = dist<<32 | (32767-gidx)<<17 | tag   (u64-max == np.argmax first-occ:
//        dist>=0 -> IEEE-bit monotone; inverted idx -> lowest-index ties)
//   wx/wy/wz = coord_bits<<12 | tag
// tags monotone 1..2047 (12 bits); ws 0xAA poison -> tag field 0xAAA never
// matches; LLC parity double-buffer (slot reuse at s+2 provably
// post-consumption); LDS part[] zero-init kills stale-tag aliasing.
// Numerics bit-exact vs numpy: contract off, (dx*dx+dy*dy)+dz*dz, no fma.
__global__ __launch_bounds__(FPS_T) void fps_kernel(const float* __restrict__ pts,
                                                    float* __restrict__ out,
                                                    ull* __restrict__ ws) {
#pragma clang fp contract(off)
    __shared__ float4 sc[PTS];          // 64 KiB coords
    __shared__ ull part[8];             // tagged per-scan-wave partials
    __shared__ float swx, swy, swz;     // winner coords
    __shared__ unsigned swtag;          // winner tag (release/acquire)

    const int blk = blockIdx.x;
    const int b = blk & 15;             // batch; same-batch blocks share blk%8
    const int j = blk >> 4;             // block-within-batch 0..7
    const int tid = threadIdx.x;
    const float* __restrict__ X = pts + (size_t)b * 3 * FPS_N;
    const float* __restrict__ Y = X + FPS_N;
    const float* __restrict__ Z = Y + FPS_N;
    const int off = j * PTS;
    float* __restrict__ outb = out + (size_t)b * 3 * FPS_M;
    ull* __restrict__ wsb = ws + (size_t)b * 64;  // 2 par x 4 lines x 8 slots

    for (int q = tid; q < PTS; q += FPS_T)        // one-time coord stage
        sc[q] = make_float4(X[off + q], Y[off + q], Z[off + q], 0.0f);
    if (tid < 8) part[tid] = 0;                   // kill stale-tag aliasing
    if (tid == 8) swtag = 0;
    __syncthreads();                              // only barrier (pre-loop)

    if (tid < 64) {
        // ================= comm wave =================
        const int lane = tid;
        if (j == 0 && lane == 0) {                // selection 0 = point 0
            outb[0]         = X[0];
            outb[FPS_M]     = Y[0];
            outb[2 * FPS_M] = Z[0];
        }
        for (int s = 1; s < FPS_M; ++s) {
            const unsigned tag = (unsigned)s;
            // ---- gather 8 tagged partials from LDS (trickle-in) ----
            ull pv = 0;
            bool ok = (lane >= 8);
            for (int it = 0; it < (1 << 25); ++it) {
                if (!ok) {
                    pv = __hip_atomic_load(&part[lane], __ATOMIC_RELAXED,
                                           __HIP_MEMORY_SCOPE_WORKGROUP);
                    ok = ((unsigned)(pv & 0xFFFull) == tag);
                }
                if (__all(ok)) break;
            }
            // block-best: 3 DPP steps, result in lane 7
            ull v = (lane < 8) ? pv : 0;
            v = max8_u64_dpp(v);
            ull* grp = wsb + (s & 1) * 32;        // parity line group (256 B)
            if (lane == 7) {
                // block-best coords from OWN LDS (no global fetch)
                const unsigned gidx = 32767u - (unsigned)((v >> 17) & 0x7FFFull);
                float4 c = sc[gidx - off];
                // 4 relaxed stores, all in flight concurrently
                __hip_atomic_store(grp + 0 * 8 + j, v,
                                   __ATOMIC_RELAXED, __HIP_MEMORY_SCOPE_AGENT);
                __hip_atomic_store(grp + 1 * 8 + j,
                                   ((ull)__float_as_uint(c.x) << 12) | tag,
                                   __ATOMIC_RELAXED, __HIP_MEMORY_SCOPE_AGENT);
                __hip_atomic_store(grp + 2 * 8 + j,
                                   ((ull)__float_as_uint(c.y) << 12) | tag,
                                   __ATOMIC_RELAXED, __HIP_MEMORY_SCOPE_AGENT);
                __hip_atomic_store(grp + 3 * 8 + j,
                                   ((ull)__float_as_uint(c.z) << 12) | tag,
                                   __ATOMIC_RELAXED, __HIP_MEMORY_SCOPE_AGENT);
            }
            // ---- poll: 32 lanes, one word each (4 lines, self-throttled) ----
            ull* pa = grp + lane;
            ok = (lane >= 32);
            ull val = 0;
            for (int it = 0; it < (1 << 24); ++it) {
                if (!ok) {
                    val = __hip_atomic_load(pa, __ATOMIC_RELAXED,
                                            __HIP_MEMORY_SCOPE_AGENT);
                    ok = ((unsigned)(val & 0xFFFull) == tag);
                }
                if (__all(ok)) break;
            }
            // ---- winner: 3 DPP steps over wd lanes (0-7), result lane 7 ----
            ull r = (lane < 8) ? val : 0;
            r = max8_u64_dpp(r);
            r = __shfl(r, 7);                     // broadcast winner word
            const int jw = (32767 - (int)((r >> 17) & 0x7FFFull)) >> 12;
            // self-selected lanes post winner coords from their own payload
            const float cf = __uint_as_float((unsigned)(val >> 12));
            if (lane == 8 + jw) {
                swx = cf;
                if (j == 0) outb[s] = cf;
            } else if (lane == 16 + jw) {
                swy = cf;
                if (j == 0) outb[FPS_M + s] = cf;
            } else if (lane == 24 + jw) {
                swz = cf;
                if (j == 0) outb[2 * FPS_M + s] = cf;
            }
            // release: wave-wide lgkmcnt drain orders the coord ds_writes
            if (lane == 0)
                __hip_atomic_store(&swtag, tag, __ATOMIC_RELEASE,
                                   __HIP_MEMORY_SCOPE_WORKGROUP);
        }
    } else {
        // ================= scan waves =================
        const int st = tid - 64;                  // 0..511
        const int wv = (tid >> 6) - 1;            // scan wave 0..7
        const int lane = tid & 63;
        float dist[PPT];
#pragma unroll
        for (int k = 0; k < PPT; ++k) dist[k] = 1e10f;
        float lx = X[0], ly = Y[0], lz = Z[0];    // first selection = index 0

        for (int s = 1; s < FPS_M; ++s) {
            const unsigned tag = (unsigned)s;
            float bd = -1.0f;
            int bi = 0;
#pragma unroll
            for (int k = 0; k < PPT; ++k) {
                const int q = k * SCT + st;
                float4 c = sc[q];                            // ds_read_b128
                float dx = c.x - lx, dy = c.y - ly, dz = c.z - lz;
                float d = (dx * dx + dy * dy) + dz * dz;     // numpy order
                float nd = d < dist[k] ? d : dist[k];
                dist[k] = nd;
                if (nd > bd) { bd = nd; bi = q; }            // strict >
            }
            // pack once; 6 DPP steps -> wave max in lane 63
            ull w = ((ull)__float_as_uint(bd) << 32)
                  | ((ull)(32767u - (unsigned)(off + bi)) << 17)
                  | (ull)tag;
            w = wave_max_u64_dpp(w);
            if (lane == 63)
                __hip_atomic_store(&part[wv], w, __ATOMIC_RELAXED,
                                   __HIP_MEMORY_SCOPE_WORKGROUP);
            // wait for winner(s): LDS broadcast spin, acquire orders coord reads
            for (int it = 0; it < (1 << 25); ++it) {
                unsigned t = __hip_atomic_load(&swtag, __ATOMIC_ACQUIRE,
                                               __HIP_MEMORY_SCOPE_WORKGROUP);
                if (t == tag) break;
            }
            lx = swx;
            ly = swy;
            lz = swz;
        }
    }
}

extern "C" void kernel_launch(void* const* d_in, const int* in_sizes, int n_in,
                              void* d_out, int out_size, void* d_ws, size_t ws_size,
                              hipStream_t stream) {
    const float* pts = (const float*)d_in[0];   // [16, 3, 32768] fp32
    float* out = (float*)d_out;                 // [16, 3, 2048] fp32
    ull* ws = (ull*)d_ws;                       // 16 batches x 64 words = 8 KB
    void* args[] = { (void*)&pts, (void*)&out, (void*)&ws };
    hipLaunchCooperativeKernel((const void*)fps_kernel,
                               dim3(FPS_B * BLK_PER_B), dim3(FPS_T),
                               args, 0, stream);
}